// Round 1
// baseline (976.569 us; speedup 1.0000x reference)
//
#include <hip/hip_runtime.h>
#include <hip/hip_bf16.h>

// GCN 2-layer: h1 = relu(Agg(x@W1) + b1); out = Agg(h1@W2) + b2
// Agg(h)[i] = sum_{e:(s->i)} h[s]*dis[s]*dis[i] + h[i]*dis[i]^2
// dis = rsqrt(indeg+1)  (self-loop included in degree)

#define FOUT 64

// ---- degree / normalization ----------------------------------------------
__global__ void deg_init(float* deg, int n) {
    int i = blockIdx.x * 256 + threadIdx.x;
    if (i < n) deg[i] = 1.0f;  // self-loop contributes 1
}

__global__ void deg_count(const int* __restrict__ dst, float* deg, int E) {
    int e = blockIdx.x * 256 + threadIdx.x;
    if (e < E) atomicAdd(&deg[dst[e]], 1.0f);
}

__global__ void deg_rsqrt(float* deg, int n) {
    int i = blockIdx.x * 256 + threadIdx.x;
    if (i < n) deg[i] = rsqrtf(deg[i]);  // deg >= 1 always
}

// ---- GEMM: H[n x 64] = X[n x K] @ W[K x 64] ------------------------------
// 64 rows per block, full K in LDS, 256 threads, 4x4 microtile per thread.
template <int K>
__global__ __launch_bounds__(256) void gemm_xw(const float* __restrict__ X,
                                               const float* __restrict__ W,
                                               float* __restrict__ H, int n) {
    constexpr int KP = K + 4;  // pad keeps float4 alignment, breaks bank conflicts
    __shared__ float xs[64 * KP];
    __shared__ float ws[K * 64];
    const int tid  = threadIdx.x;
    const int row0 = blockIdx.x * 64;

    // stage X tile (zeros for out-of-range rows)
    for (int idx = tid; idx < 64 * K / 4; idx += 256) {
        int r = (idx * 4) / K;
        int c = (idx * 4) % K;
        float4 v = make_float4(0.f, 0.f, 0.f, 0.f);
        if (row0 + r < n) v = *(const float4*)&X[(size_t)(row0 + r) * K + c];
        *(float4*)&xs[r * KP + c] = v;
    }
    // stage W (row-major [K][64])
    for (int idx = tid; idx < K * 64 / 4; idx += 256) {
        *(float4*)&ws[idx * 4] = *(const float4*)&W[idx * 4];
    }
    __syncthreads();

    const int tr = tid >> 4;   // 0..15 -> rows tr*4..tr*4+3
    const int tc = tid & 15;   // 0..15 -> cols tc*4..tc*4+3
    float acc[4][4];
#pragma unroll
    for (int i = 0; i < 4; i++)
#pragma unroll
        for (int j = 0; j < 4; j++) acc[i][j] = 0.f;

    for (int k = 0; k < K; k += 4) {
        float4 xv[4], wv[4];
#pragma unroll
        for (int i = 0; i < 4; i++) xv[i] = *(float4*)&xs[(tr * 4 + i) * KP + k];
#pragma unroll
        for (int kk = 0; kk < 4; kk++) wv[kk] = *(float4*)&ws[(k + kk) * 64 + tc * 4];
#pragma unroll
        for (int i = 0; i < 4; i++) {
            float xi[4] = {xv[i].x, xv[i].y, xv[i].z, xv[i].w};
#pragma unroll
            for (int kk = 0; kk < 4; kk++) {
                acc[i][0] = fmaf(xi[kk], wv[kk].x, acc[i][0]);
                acc[i][1] = fmaf(xi[kk], wv[kk].y, acc[i][1]);
                acc[i][2] = fmaf(xi[kk], wv[kk].z, acc[i][2]);
                acc[i][3] = fmaf(xi[kk], wv[kk].w, acc[i][3]);
            }
        }
    }
#pragma unroll
    for (int i = 0; i < 4; i++) {
        int r = row0 + tr * 4 + i;
        if (r < n) {
            float4 o = make_float4(acc[i][0], acc[i][1], acc[i][2], acc[i][3]);
            *(float4*)&H[(size_t)r * FOUT + tc * 4] = o;
        }
    }
}

// ---- edge scatter: agg[dst] += h[src]*dis[src]*dis[dst] ------------------
// one wave per edge, lane = feature
__global__ __launch_bounds__(256) void scatter_edges(
    const float* __restrict__ H, const int* __restrict__ src,
    const int* __restrict__ dst, const float* __restrict__ dis,
    float* __restrict__ agg, int E) {
    int e = blockIdx.x * 4 + (threadIdx.x >> 6);
    if (e >= E) return;
    int j = threadIdx.x & 63;
    int s = src[e], d = dst[e];
    float nm = dis[s] * dis[d];
    atomicAdd(&agg[(size_t)d * FOUT + j], H[(size_t)s * FOUT + j] * nm);
}

// ---- epilogues -----------------------------------------------------------
// layer1: out = relu(agg + h*dis^2 + b)
__global__ void epi_relu(float* __restrict__ out, const float* __restrict__ h,
                         const float* __restrict__ dis, const float* __restrict__ b,
                         int total) {
    int idx = blockIdx.x * 256 + threadIdx.x;
    if (idx >= total) return;
    int i = idx >> 6, j = idx & 63;
    float d = dis[i];
    float v = out[idx] + h[idx] * (d * d) + b[j];
    out[idx] = fmaxf(v, 0.0f);
}

// layer2: out = agg + h*dis^2 + b
__global__ void epi_add(float* __restrict__ out, const float* __restrict__ h,
                        const float* __restrict__ dis, const float* __restrict__ b,
                        int total) {
    int idx = blockIdx.x * 256 + threadIdx.x;
    if (idx >= total) return;
    int i = idx >> 6, j = idx & 63;
    float d = dis[i];
    out[idx] = out[idx] + h[idx] * (d * d) + b[j];
}

extern "C" void kernel_launch(void* const* d_in, const int* in_sizes, int n_in,
                              void* d_out, int out_size, void* d_ws, size_t ws_size,
                              hipStream_t stream) {
    const float* x  = (const float*)d_in[0];
    const int*   ei = (const int*)d_in[1];
    const float* W1 = (const float*)d_in[2];
    const float* b1 = (const float*)d_in[3];
    const float* W2 = (const float*)d_in[4];
    const float* b2 = (const float*)d_in[5];

    const int n = in_sizes[0] / 128;
    const int E = in_sizes[1] / 2;
    const int* srcp = ei;
    const int* dstp = ei + E;

    float* out = (float*)d_out;
    float* ws  = (float*)d_ws;
    float* dis = ws;                                   // n floats
    float* h   = ws + ((size_t)(n + 255) / 256) * 256; // n*64 floats

    const int total = n * FOUT;

    // degree -> dis
    deg_init<<<(n + 255) / 256, 256, 0, stream>>>(dis, n);
    deg_count<<<(E + 255) / 256, 256, 0, stream>>>(dstp, dis, E);
    deg_rsqrt<<<(n + 255) / 256, 256, 0, stream>>>(dis, n);

    // layer 1: h = x@W1 ; d_out = Agg(h) ; d_out = relu(d_out + h*dis^2 + b1)
    gemm_xw<128><<<(n + 63) / 64, 256, 0, stream>>>(x, W1, h, n);
    hipMemsetAsync(d_out, 0, (size_t)total * sizeof(float), stream);
    scatter_edges<<<(E + 3) / 4, 256, 0, stream>>>(h, srcp, dstp, dis, out, E);
    epi_relu<<<(total + 255) / 256, 256, 0, stream>>>(out, h, dis, b1, total);

    // layer 2: h = d_out@W2 ; d_out = Agg(h) + h*dis^2 + b2
    gemm_xw<64><<<(n + 63) / 64, 256, 0, stream>>>(out, W2, h, n);
    hipMemsetAsync(d_out, 0, (size_t)total * sizeof(float), stream);
    scatter_edges<<<(E + 3) / 4, 256, 0, stream>>>(h, srcp, dstp, dis, out, E);
    epi_add<<<(total + 255) / 256, 256, 0, stream>>>(out, h, dis, b2, total);
}

// Round 2
// 478.405 us; speedup vs baseline: 2.0413x; 2.0413x over previous
//
#include <hip/hip_runtime.h>
#include <hip/hip_bf16.h>

// GCN 2-layer via CSR gather (no fp32 atomics):
//   dis = rsqrt(indeg_by_dst + 1)
//   hs  = (x@W) * dis[row]          (GEMM epilogue)
//   out[i] = act( dis[i] * (hs[i] + sum_{s in N(i)} hs[s]) + b )
// CSR (rowptr/col by dst) built once per call, shared by both layers.

#define FOUT 64

// ---- degree --------------------------------------------------------------
__global__ void deg_count(const int* __restrict__ dst, int* __restrict__ deg, int E) {
    int e = blockIdx.x * 256 + threadIdx.x;
    if (e < E) atomicAdd(&deg[dst[e]], 1);
}

__global__ void dis_kernel(const int* __restrict__ deg, float* __restrict__ dis, int n) {
    int i = blockIdx.x * 256 + threadIdx.x;
    if (i < n) dis[i] = rsqrtf((float)deg[i] + 1.0f);  // +1 self-loop
}

// ---- exclusive scan of deg -> rowptr (chunk=1024/block) ------------------
__global__ __launch_bounds__(256) void scanA(const int* __restrict__ deg,
                                             int* __restrict__ bsum, int n) {
    __shared__ int ts[256];
    int b = blockIdx.x, t = threadIdx.x;
    int base = b * 1024 + t * 4;
    int s = 0;
#pragma unroll
    for (int k = 0; k < 4; k++)
        if (base + k < n) s += deg[base + k];
    ts[t] = s;
    __syncthreads();
    for (int off = 128; off > 0; off >>= 1) {
        if (t < off) ts[t] += ts[t + off];
        __syncthreads();
    }
    if (t == 0) bsum[b] = ts[0];
}

__global__ void scanB(int* __restrict__ bsum, int nb, int* __restrict__ rowptr, int n) {
    if (threadIdx.x == 0 && blockIdx.x == 0) {
        int run = 0;
        for (int b = 0; b < nb; b++) {
            int t = bsum[b];
            bsum[b] = run;
            run += t;
        }
        rowptr[n] = run;  // == E
    }
}

__global__ __launch_bounds__(256) void scanC(const int* __restrict__ deg,
                                             const int* __restrict__ bsum,
                                             int* __restrict__ rowptr, int n) {
    __shared__ int ts[256];
    int b = blockIdx.x, t = threadIdx.x;
    int base = b * 1024 + t * 4;
    int v[4], s = 0;
#pragma unroll
    for (int k = 0; k < 4; k++) {
        v[k] = (base + k < n) ? deg[base + k] : 0;
        s += v[k];
    }
    ts[t] = s;
    __syncthreads();
    // Hillis-Steele inclusive scan
    for (int off = 1; off < 256; off <<= 1) {
        int x = (t >= off) ? ts[t - off] : 0;
        __syncthreads();
        ts[t] += x;
        __syncthreads();
    }
    int pre = bsum[b] + ts[t] - s;  // exclusive prefix for this thread
#pragma unroll
    for (int k = 0; k < 4; k++) {
        if (base + k < n) rowptr[base + k] = pre;
        pre += v[k];
    }
}

// ---- edge placement into CSR ---------------------------------------------
__global__ void place_edges(const int* __restrict__ src, const int* __restrict__ dst,
                            const int* __restrict__ rowptr, int* __restrict__ cursor,
                            int* __restrict__ col, int E) {
    int e = blockIdx.x * 256 + threadIdx.x;
    if (e < E) {
        int d = dst[e];
        int p = atomicAdd(&cursor[d], 1);
        col[rowptr[d] + p] = src[e];
    }
}

// ---- GEMM: HS[n x 64] = (X[n x K] @ W[K x 64]) * dis[row] ----------------
template <int K>
__global__ __launch_bounds__(256) void gemm_xw(const float* __restrict__ X,
                                               const float* __restrict__ W,
                                               const float* __restrict__ dis,
                                               float* __restrict__ HS, int n) {
    constexpr int KP = K + 4;
    __shared__ float xs[64 * KP];
    __shared__ float ws[K * 64];
    const int tid  = threadIdx.x;
    const int row0 = blockIdx.x * 64;

    for (int idx = tid; idx < 64 * K / 4; idx += 256) {
        int r = (idx * 4) / K;
        int c = (idx * 4) % K;
        float4 v = make_float4(0.f, 0.f, 0.f, 0.f);
        if (row0 + r < n) v = *(const float4*)&X[(size_t)(row0 + r) * K + c];
        *(float4*)&xs[r * KP + c] = v;
    }
    for (int idx = tid; idx < K * 64 / 4; idx += 256) {
        *(float4*)&ws[idx * 4] = *(const float4*)&W[idx * 4];
    }
    __syncthreads();

    const int tr = tid >> 4;
    const int tc = tid & 15;
    float acc[4][4];
#pragma unroll
    for (int i = 0; i < 4; i++)
#pragma unroll
        for (int j = 0; j < 4; j++) acc[i][j] = 0.f;

    for (int k = 0; k < K; k += 4) {
        float4 xv[4], wv[4];
#pragma unroll
        for (int i = 0; i < 4; i++) xv[i] = *(float4*)&xs[(tr * 4 + i) * KP + k];
#pragma unroll
        for (int kk = 0; kk < 4; kk++) wv[kk] = *(float4*)&ws[(k + kk) * 64 + tc * 4];
#pragma unroll
        for (int i = 0; i < 4; i++) {
            float xi[4] = {xv[i].x, xv[i].y, xv[i].z, xv[i].w};
#pragma unroll
            for (int kk = 0; kk < 4; kk++) {
                acc[i][0] = fmaf(xi[kk], wv[kk].x, acc[i][0]);
                acc[i][1] = fmaf(xi[kk], wv[kk].y, acc[i][1]);
                acc[i][2] = fmaf(xi[kk], wv[kk].z, acc[i][2]);
                acc[i][3] = fmaf(xi[kk], wv[kk].w, acc[i][3]);
            }
        }
    }
#pragma unroll
    for (int i = 0; i < 4; i++) {
        int r = row0 + tr * 4 + i;
        if (r < n) {
            float dr = dis[r];
            float4 o = make_float4(acc[i][0] * dr, acc[i][1] * dr,
                                   acc[i][2] * dr, acc[i][3] * dr);
            *(float4*)&HS[(size_t)r * FOUT + tc * 4] = o;
        }
    }
}

// ---- aggregate: one wave per node, lane = feature ------------------------
template <bool RELU>
__global__ __launch_bounds__(256) void aggregate(
    const float* __restrict__ hs, const int* __restrict__ rowptr,
    const int* __restrict__ col, const float* __restrict__ dis,
    const float* __restrict__ bias, float* __restrict__ out, int n) {
    int i = blockIdx.x * 4 + (threadIdx.x >> 6);
    if (i >= n) return;
    int j = threadIdx.x & 63;
    int beg = rowptr[i], end = rowptr[i + 1];
    float acc = hs[(size_t)i * FOUT + j];  // self-loop term

    for (int chunk = beg; chunk < end; chunk += 64) {
        int m = end - chunk;
        if (m > 64) m = 64;
        // wave-coalesced load of up to 64 column indices
        int c = (j < m) ? col[chunk + j] : 0;
        int q = 0;
        for (; q + 4 <= m; q += 4) {
            int s0 = __shfl(c, q);
            int s1 = __shfl(c, q + 1);
            int s2 = __shfl(c, q + 2);
            int s3 = __shfl(c, q + 3);
            float v0 = hs[(size_t)s0 * FOUT + j];
            float v1 = hs[(size_t)s1 * FOUT + j];
            float v2 = hs[(size_t)s2 * FOUT + j];
            float v3 = hs[(size_t)s3 * FOUT + j];
            acc += v0 + v1 + v2 + v3;
        }
        for (; q < m; q++) {
            int s = __shfl(c, q);
            acc += hs[(size_t)s * FOUT + j];
        }
    }
    float v = dis[i] * acc + bias[j];
    if (RELU) v = fmaxf(v, 0.0f);
    out[(size_t)i * FOUT + j] = v;
}

extern "C" void kernel_launch(void* const* d_in, const int* in_sizes, int n_in,
                              void* d_out, int out_size, void* d_ws, size_t ws_size,
                              hipStream_t stream) {
    const float* x  = (const float*)d_in[0];
    const int*   ei = (const int*)d_in[1];
    const float* W1 = (const float*)d_in[2];
    const float* b1 = (const float*)d_in[3];
    const float* W2 = (const float*)d_in[4];
    const float* b2 = (const float*)d_in[5];

    const int n = in_sizes[0] / 128;
    const int E = in_sizes[1] / 2;
    const int* srcp = ei;
    const int* dstp = ei + E;

    float* out = (float*)d_out;

    // workspace layout (all offsets kept 16B-aligned)
    int*   deg    = (int*)d_ws;            // n
    int*   cursor = deg + n;               // n
    int*   rowptr = cursor + n;            // n+1 (padded to n+4)
    int*   bsum   = rowptr + n + 4;        // up to 4096 blocks
    int*   col    = bsum + 4096;           // E
    float* dis    = (float*)(col + E);     // n
    float* hs     = dis + n;               // n*64

    const int nb = (n + 1023) / 1024;

    // zero deg + cursor (adjacent)
    hipMemsetAsync(d_ws, 0, (size_t)2 * n * sizeof(int), stream);

    // degree -> dis, CSR build
    deg_count<<<(E + 255) / 256, 256, 0, stream>>>(dstp, deg, E);
    dis_kernel<<<(n + 255) / 256, 256, 0, stream>>>(deg, dis, n);
    scanA<<<nb, 256, 0, stream>>>(deg, bsum, n);
    scanB<<<1, 64, 0, stream>>>(bsum, nb, rowptr, n);
    scanC<<<nb, 256, 0, stream>>>(deg, bsum, rowptr, n);
    place_edges<<<(E + 255) / 256, 256, 0, stream>>>(srcp, dstp, rowptr, cursor, col, E);

    // layer 1: hs = (x@W1)*dis ; out = relu(dis*(hs_self + sum hs[nbr]) + b1)
    gemm_xw<128><<<(n + 63) / 64, 256, 0, stream>>>(x, W1, dis, hs, n);
    aggregate<true><<<(n + 3) / 4, 256, 0, stream>>>(hs, rowptr, col, dis, b1, out, n);

    // layer 2: hs = (out@W2)*dis ; out = dis*(hs_self + sum hs[nbr]) + b2
    gemm_xw<64><<<(n + 63) / 64, 256, 0, stream>>>(out, W2, dis, hs, n);
    aggregate<false><<<(n + 3) / 4, 256, 0, stream>>>(hs, rowptr, col, dis, b2, out, n);
}